// Round 16
// baseline (369.102 us; speedup 1.0000x reference)
//
#include <hip/hip_runtime.h>
#include <math.h>

// Problem constants
#define BB 16
#define TT 2048
#define DD 512
#define WW 12
#define TQ 512
#define NROWS (BB * TQ)

typedef _Float16 f16;
typedef __attribute__((ext_vector_type(8))) _Float16 f16x8;
typedef __attribute__((ext_vector_type(4))) _Float16 f16x4;
typedef __attribute__((ext_vector_type(4))) float f32x4;

#define MFMA16(a, b, c) __builtin_amdgcn_mfma_f32_16x16x32_f16((a), (b), (c), 0, 0, 0)

// ws layout
#define WS_IDS  0u
#define WS_W16  (512u * 1024u)                  // 3072 x 512 f16 = 3 MB
#define WS_H16  (4u * 1024u * 1024u)            // 8192 x 512 f16 = 8 MB (ping)
#define WS_GI   (12u * 1024u * 1024u)           // 32768 x 1536 f16 = 96 MB
#define WS_X16  (108ull * 1024ull * 1024ull)    // 32768 x 512 f16 = 32 MB
#define WS_NEED_X16 (140ull * 1024ull * 1024ull)

// prep grid split
#define SEL_BLOCKS 2048
#define W_BLOCKS   1536
#define X_BLOCKS   16384

__device__ __forceinline__ float fsigm(float v) { return 1.0f / (1.0f + __expf(-v)); }
__device__ __forceinline__ float ftanh(float v) {
    float a = fabsf(v);
    float t = __expf(-2.0f * a);
    float r = (1.0f - t) / (1.0f + t);
    return copysignf(r, v);
}

__device__ __forceinline__ f16x8 cvt8(float4 a, float4 b) {
    f16x8 r;
    r[0] = (_Float16)a.x; r[1] = (_Float16)a.y; r[2] = (_Float16)a.z; r[3] = (_Float16)a.w;
    r[4] = (_Float16)b.x; r[5] = (_Float16)b.y; r[6] = (_Float16)b.z; r[7] = (_Float16)b.w;
    return r;
}

// -------- Kernel 1: merged prep = select + w16 + x16 (round-12 proven) ------
__global__ __launch_bounds__(256, 4) void prep_kernel(
    const float* __restrict__ x, int* __restrict__ ids,
    const float* __restrict__ wi, const float* __restrict__ wh,
    f16* __restrict__ w16, f16* __restrict__ x16, int has_x16)
{
    const int bid = blockIdx.x;
    const int tid = threadIdx.x;

    if (bid >= SEL_BLOCKS) {
        int rel = bid - SEL_BLOCKS;
        if (rel < W_BLOCKS) {
            const int PER = 3 * DD * DD / 4;
            int i = rel * 256 + tid;
            float4 v;
            if (i < PER) v = ((const float4*)wi)[i];
            else         v = ((const float4*)wh)[i - PER];
            f16x4 o;
            o[0] = (_Float16)v.x; o[1] = (_Float16)v.y; o[2] = (_Float16)v.z; o[3] = (_Float16)v.w;
            *(f16x4*)(w16 + (size_t)i * 4) = o;
        } else {
            int j = (rel - W_BLOCKS) * 256 + tid;
            float4 v = ((const float4*)x)[j];
            f16x4 o;
            o[0] = (_Float16)v.x; o[1] = (_Float16)v.y; o[2] = (_Float16)v.z; o[3] = (_Float16)v.w;
            *(f16x4*)(x16 + (size_t)j * 4) = o;
        }
        return;
    }

    const int wid = tid >> 6, lane = tid & 63;
    const int swz = (bid & 7) * 256 + (bid >> 3);
    const int n = swz * 4 + wid;
    const int b = n >> 9, qi = n & 511;

    int t = (qi == TQ - 1) ? (TT - 1)
          : (int)((double)qi * ((double)(TT - 1) / (double)(TQ - 1)));
    int j0 = t - (WW - 1); if (j0 < 0) j0 = 0;
    int j1 = t + (WW - 1); if (j1 > TT - 1) j1 = TT - 1;
    const int ncand = j1 - j0 + 1;

    const int c = lane & 3, i = lane >> 2;
    const float* qrow = x + ((size_t)b * TT + t) * DD + i * 4;

    float4 q[8];
#pragma unroll
    for (int it = 0; it < 8; ++it) q[it] = *(const float4*)(qrow + it * 64);

    double sv[6];
#pragma unroll
    for (int r = 0; r < 6; ++r) {
        int cc = r * 4 + c;
        int jr = j0 + cc; if (jr > j1) jr = j1;
        const float* krow = x + ((size_t)b * TT + jr) * DD + i * 4;
        double s0 = 0.0, s1 = 0.0;
#pragma unroll
        for (int it = 0; it < 8; ++it) {
            float4 kv = *(const float4*)(krow + it * 64);
            s0 = fma((double)q[it].x, (double)kv.x, s0);
            s1 = fma((double)q[it].y, (double)kv.y, s1);
            s0 = fma((double)q[it].z, (double)kv.z, s0);
            s1 = fma((double)q[it].w, (double)kv.w, s1);
        }
        sv[r] = s0 + s1;
    }

#pragma unroll
    for (int r = 0; r < 6; ++r) {
        double v = sv[r];
        v += __shfl_xor(v, 4);
        v += __shfl_xor(v, 8);
        v += __shfl_xor(v, 16);
        v += __shfl_xor(v, 32);
        sv[r] = v;
    }

    const int rr = lane >> 2;
    double sj = sv[0];
    sj = (rr == 1) ? sv[1] : sj;
    sj = (rr == 2) ? sv[2] : sj;
    sj = (rr == 3) ? sv[3] : sj;
    sj = (rr == 4) ? sv[4] : sj;
    sj = (rr == 5) ? sv[5] : sj;
    bool valid = lane < ncand;
    if (!valid) sj = -1.0e300;

    int rank = 0;
    for (int kk = 0; kk < 2 * WW - 1; ++kk) {
        if (kk >= ncand) break;
        double bs = __shfl(sj, kk);
        rank += (bs > sj || (bs == sj && kk < lane)) ? 1 : 0;
    }
    bool sel = valid && (rank < WW);
    unsigned long long m = __ballot(sel);
    if (sel) {
        int pos = __popcll(m & ((1ull << lane) - 1ull));
        ids[(size_t)n * WW + pos] = j0 + lane;
    }
}

// -------- Kernel 3: GI = x @ w_ih.T + b_ih (round-12 proven) ---------------
template<bool X16PATH>
__global__ __launch_bounds__(256, 2) void gi_gemm_kernel(
    const float* __restrict__ x,
    const f16* __restrict__ x16,
    const f16* __restrict__ w16,        // rows 0..1535 = w_ih
    const float* __restrict__ b_ih,
    f16* __restrict__ gi)               // [32768][1536]
{
    __shared__ __align__(16) char sB[2][16 * 1024];
    __shared__ __align__(16) char sX[2][16 * 1024];

    const int tid = threadIdx.x;
    const int lane = tid & 63, wid = tid >> 6;
    const int wm = wid >> 1, wn = wid & 1;
    const int l15 = lane & 15, lhi = lane >> 4;
    const int bid = blockIdx.x;
    const int xcd = bid & 7, idx = bid >> 3;
    const int rb = xcd * 32 + idx / 12;
    const int cb = idx % 12;
    const int row0 = rb * 128, c0 = cb * 128;

    const int slot = lane & 3, lc = lane >> 2;
    const f16* bsrc[4]; int bdst[4];
#pragma unroll
    for (int ii = 0; ii < 4; ++ii) {
        int ch = wid * 4 + ii;
        int half = ch >> 3, cg = ch & 7;
        int col = cg * 16 + lc;
        bsrc[ii] = w16 + ((size_t)(c0 + col) * 512 + half * 32
                          + (size_t)((slot ^ ((col >> 1) & 3)) * 8));
        bdst[ii] = half * 8192 + cg * 1024;
    }

    const f16* x16src[4]; int x16dst[4];
    const float* xps[2]; int xdst[2];
    if (X16PATH) {
        const int xrl = lane >> 2, xslot = lane & 3;
        const int xswz = (xslot ^ ((xrl >> 1) & 3)) * 8;
#pragma unroll
        for (int ii = 0; ii < 4; ++ii) {
            int ch2 = wid * 4 + ii;
            int hh = ch2 >> 3, ch = ch2 & 7;
            x16src[ii] = x16 + ((size_t)(row0 + ch * 16 + xrl) * 512 + hh * 32 + xswz);
            x16dst[ii] = hh * 8192 + ch * 1024;
        }
    } else {
#pragma unroll
        for (int seg = 0; seg < 2; ++seg) {
            int row = seg * 64 + (tid >> 2);
            int chunk = (tid & 3) ^ ((row >> 1) & 3);
            xps[seg] = x + (size_t)(row0 + row) * DD + chunk * 8;
            xdst[seg] = seg * 4096 + tid * 16;
        }
    }

    const int swzo = (lhi ^ ((l15 >> 1) & 3)) * 16;
    const int aBase = (wm * 64 + l15) * 64 + swzo;
    const int bBase = (wn * 64 + l15) * 64 + swzo;

    f32x4 acc[4][4];
#pragma unroll
    for (int mf = 0; mf < 4; ++mf)
#pragma unroll
        for (int nf = 0; nf < 4; ++nf) { f32x4 z = {0.f,0.f,0.f,0.f}; acc[mf][nf] = z; }

    {
#pragma unroll
        for (int ii = 0; ii < 4; ++ii)
            __builtin_amdgcn_global_load_lds(
                (const __attribute__((address_space(1))) unsigned*)bsrc[ii],
                (__attribute__((address_space(3))) unsigned*)(&sB[0][0] + bdst[ii]), 16, 0, 0);
        if (X16PATH) {
#pragma unroll
            for (int ii = 0; ii < 4; ++ii)
                __builtin_amdgcn_global_load_lds(
                    (const __attribute__((address_space(1))) unsigned*)x16src[ii],
                    (__attribute__((address_space(3))) unsigned*)(&sX[0][0] + x16dst[ii]), 16, 0, 0);
        } else {
#pragma unroll
            for (int seg = 0; seg < 2; ++seg)
#pragma unroll
                for (int h = 0; h < 2; ++h) {
                    float4 a0 = *(const float4*)(xps[seg] + h * 32);
                    float4 a1 = *(const float4*)(xps[seg] + h * 32 + 4);
                    *(f16x8*)(&sX[0][0] + h * 8192 + xdst[seg]) = cvt8(a0, a1);
                }
        }
    }

    int cur = 0;
    for (int ks = 0; ks < 8; ++ks) {
        asm volatile("s_waitcnt vmcnt(0)" ::: "memory");
        __syncthreads();

        const int kn = (ks + 1) * 64;
        float4 a[2][2][2];
        if (ks < 7) {
#pragma unroll
            for (int ii = 0; ii < 4; ++ii)
                __builtin_amdgcn_global_load_lds(
                    (const __attribute__((address_space(1))) unsigned*)(bsrc[ii] + kn),
                    (__attribute__((address_space(3))) unsigned*)(&sB[cur ^ 1][0] + bdst[ii]), 16, 0, 0);
            if (X16PATH) {
#pragma unroll
                for (int ii = 0; ii < 4; ++ii)
                    __builtin_amdgcn_global_load_lds(
                        (const __attribute__((address_space(1))) unsigned*)(x16src[ii] + kn),
                        (__attribute__((address_space(3))) unsigned*)(&sX[cur ^ 1][0] + x16dst[ii]), 16, 0, 0);
            } else {
#pragma unroll
                for (int seg = 0; seg < 2; ++seg)
#pragma unroll
                    for (int h = 0; h < 2; ++h) {
                        a[seg][h][0] = *(const float4*)(xps[seg] + kn + h * 32);
                        a[seg][h][1] = *(const float4*)(xps[seg] + kn + h * 32 + 4);
                    }
            }
        }

        __builtin_amdgcn_s_setprio(1);
#pragma unroll
        for (int h = 0; h < 2; ++h) {
            f16x8 ax[4];
#pragma unroll
            for (int mf = 0; mf < 4; ++mf)
                ax[mf] = *(const f16x8*)(&sX[cur][0] + h * 8192 + aBase + mf * 1024);
#pragma unroll
            for (int nf = 0; nf < 4; ++nf) {
                f16x8 Bv = *(const f16x8*)(&sB[cur][0] + h * 8192 + bBase + nf * 1024);
#pragma unroll
                for (int mf = 0; mf < 4; ++mf)
                    acc[mf][nf] = MFMA16(ax[mf], Bv, acc[mf][nf]);
            }
        }
        __builtin_amdgcn_s_setprio(0);

        if (!X16PATH && ks < 7) {
#pragma unroll
            for (int seg = 0; seg < 2; ++seg)
#pragma unroll
                for (int h = 0; h < 2; ++h)
                    *(f16x8*)(&sX[cur ^ 1][0] + h * 8192 + xdst[seg]) = cvt8(a[seg][h][0], a[seg][h][1]);
        }
        cur ^= 1;
    }

#pragma unroll
    for (int nf = 0; nf < 4; ++nf) {
        int col = c0 + wn * 64 + nf * 16 + l15;
        float bi = b_ih[col];
#pragma unroll
        for (int mf = 0; mf < 4; ++mf)
#pragma unroll
            for (int r = 0; r < 4; ++r) {
                int row = row0 + wm * 64 + mf * 16 + lhi * 4 + r;
                gi[(size_t)row * 1536 + col] = (f16)(acc[mf][nf][r] + bi);
            }
    }
}

// -------- Kernel 4: step 0 elementwise (h0 = 0) ----------------------------
__global__ __launch_bounds__(256) void step0_kernel(
    const int* __restrict__ ids, const f16* __restrict__ gi,
    const float* __restrict__ b_hh, f16* __restrict__ h16w)
{
    int g = blockIdx.x * 256 + threadIdx.x;
    int row = g >> 6;
    int c8 = (g & 63) * 8;
    int src = (row >> 9) * TT + ids[(size_t)row * WW + 0];
    const f16* gr = gi + (size_t)src * 1536 + c8;
    f16x8 vr = *(const f16x8*)(gr);
    f16x8 vz = *(const f16x8*)(gr + 512);
    f16x8 vn = *(const f16x8*)(gr + 1024);
    f16x8 out;
#pragma unroll
    for (int j = 0; j < 8; ++j) {
        int col = c8 + j;
        float R = fsigm((float)vr[j] + b_hh[col]);
        float Z = fsigm((float)vz[j] + b_hh[DD + col]);
        float N = ftanh((float)vn[j] + R * b_hh[2 * DD + col]);
        out[j] = (f16)((1.0f - Z) * N);
    }
    *(f16x8*)(h16w + (size_t)row * DD + c8) = out;
}

// -------- Kernel 5: h-side GRU step (round-15 core + hoisted gathers) ------
// 256 thr / 4 waves; tile 128 rows x 64 cols; grid 512 = 64 rb x 8 cb.
// LDS 80 KB (2 blocks/CU): B 2x24KB, h 2x16KB; 8-slot-row XOR swizzle via
// pre-swizzled-source global_load_lds; vmcnt(0)+syncthreads per phase.
// Epilogue ids + h_old gathers issued BEFORE the K-loop (latency hidden).
template<bool LAST>
__global__ __launch_bounds__(256, 2) void gru_step_h_kernel(
    const int* __restrict__ ids,
    const f16* __restrict__ w16,        // rows 1536..3071 = w_hh
    const float* __restrict__ b_hh,
    const f16* __restrict__ gi,
    const f16* __restrict__ h16r,
    f16* __restrict__ h16w,
    float* __restrict__ f32w,
    int step)
{
    __shared__ __align__(16) char sB[2][24 * 1024];
    __shared__ __align__(16) char sH[2][16 * 1024];

    const int tid = threadIdx.x;
    const int lane = tid & 63, wid = tid >> 6;
    const int wm = wid >> 1, wn = wid & 1;
    const int l15 = lane & 15, lhi = lane >> 4;
    const int bid = blockIdx.x;
    const int xcd = bid & 7, idx = bid >> 3;
    const int rb = xcd * 8 + (idx & 7);
    const int cb = idx >> 3;
    const int row0 = rb * 128, c0 = cb * 64;

    const int lrow = lane >> 3, lslot = lane & 7;
    const int sswz = (lslot ^ lrow) * 8;

    const f16* bsrc[6]; int bdst[6];
#pragma unroll
    for (int ii = 0; ii < 6; ++ii) {
        int ch = wid * 6 + ii;
        int gate = ch >> 3, cg = ch & 7;
        int col = cg * 8 + lrow;
        bsrc[ii] = w16 + ((size_t)(1536 + gate * 512 + c0 + col) * 512 + sswz);
        bdst[ii] = gate * 8192 + cg * 1024 + lrow * 128 + lslot * 16;
    }
    const f16* hsrc[4]; int hdst[4];
#pragma unroll
    for (int ii = 0; ii < 4; ++ii) {
        int ch = wid * 4 + ii;
        int hrow = ch * 8 + lrow;
        hsrc[ii] = h16r + ((size_t)(row0 + hrow) * 512 + sswz);
        hdst[ii] = ch * 1024 + lrow * 128 + lslot * 16;
    }

    const int rowrd = wm * 64 + l15;
    const int colrd = wn * 32 + l15;
    int aOff[4][2], bOff[2][2];
#pragma unroll
    for (int mf = 0; mf < 4; ++mf)
#pragma unroll
        for (int h = 0; h < 2; ++h) {
            int rr2 = rowrd + mf * 16;
            aOff[mf][h] = rr2 * 128 + ((((h << 2) | lhi) ^ (rr2 & 7)) << 4);
        }
#pragma unroll
    for (int nf = 0; nf < 2; ++nf)
#pragma unroll
        for (int h = 0; h < 2; ++h) {
            int cc = colrd + nf * 16;
            bOff[nf][h] = cc * 128 + ((((h << 2) | lhi) ^ (cc & 7)) << 4);
        }

    f32x4 accR[4][2], accZ[4][2], accHN[4][2];
#pragma unroll
    for (int mf = 0; mf < 4; ++mf)
#pragma unroll
        for (int nf = 0; nf < 2; ++nf) {
            f32x4 z = {0.f, 0.f, 0.f, 0.f};
            accR[mf][nf] = z; accZ[mf][nf] = z; accHN[mf][nf] = z;
        }

    // prologue: fill buffer 0
#pragma unroll
    for (int ii = 0; ii < 6; ++ii)
        __builtin_amdgcn_global_load_lds(
            (const __attribute__((address_space(1))) unsigned*)bsrc[ii],
            (__attribute__((address_space(3))) unsigned*)(&sB[0][0] + bdst[ii]), 16, 0, 0);
#pragma unroll
    for (int ii = 0; ii < 4; ++ii)
        __builtin_amdgcn_global_load_lds(
            (const __attribute__((address_space(1))) unsigned*)hsrc[ii],
            (__attribute__((address_space(3))) unsigned*)(&sH[0][0] + hdst[ii]), 16, 0, 0);

    // hoisted epilogue gathers: complete during the K-loop (phase-0 vmcnt(0)
    // drains them; they are reads of immutable ids / h16r — no hazard)
    int srcrow[4][4];
#pragma unroll
    for (int mf = 0; mf < 4; ++mf)
#pragma unroll
        for (int r = 0; r < 4; ++r) {
            int row = row0 + wm * 64 + mf * 16 + lhi * 4 + r;
            srcrow[mf][r] = (row >> 9) * TT + ids[(size_t)row * WW + step];
        }
    f16 hvp[4][2][4];
#pragma unroll
    for (int mf = 0; mf < 4; ++mf)
#pragma unroll
        for (int nf = 0; nf < 2; ++nf) {
            int col = c0 + wn * 32 + nf * 16 + l15;
#pragma unroll
            for (int r = 0; r < 4; ++r) {
                int row = row0 + wm * 64 + mf * 16 + lhi * 4 + r;
                hvp[mf][nf][r] = h16r[(size_t)row * DD + col];
            }
        }

    int cur = 0;
    for (int ks = 0; ks < 8; ++ks) {
        asm volatile("s_waitcnt vmcnt(0)" ::: "memory");
        __syncthreads();

        const int kn = (ks + 1) * 64;
        if (ks < 7) {
#pragma unroll
            for (int ii = 0; ii < 6; ++ii)
                __builtin_amdgcn_global_load_lds(
                    (const __attribute__((address_space(1))) unsigned*)(bsrc[ii] + kn),
                    (__attribute__((address_space(3))) unsigned*)(&sB[cur ^ 1][0] + bdst[ii]), 16, 0, 0);
#pragma unroll
            for (int ii = 0; ii < 4; ++ii)
                __builtin_amdgcn_global_load_lds(
                    (const __attribute__((address_space(1))) unsigned*)(hsrc[ii] + kn),
                    (__attribute__((address_space(3))) unsigned*)(&sH[cur ^ 1][0] + hdst[ii]), 16, 0, 0);
        }

        __builtin_amdgcn_s_setprio(1);
#pragma unroll
        for (int h = 0; h < 2; ++h) {
            f16x8 ah[4];
#pragma unroll
            for (int mf = 0; mf < 4; ++mf)
                ah[mf] = *(const f16x8*)(&sH[cur][0] + aOff[mf][h]);
#pragma unroll
            for (int nf = 0; nf < 2; ++nf) {
                const char* bb = &sB[cur][0] + bOff[nf][h];
                f16x8 B0 = *(const f16x8*)(bb + 0 * 8192);
                f16x8 B1 = *(const f16x8*)(bb + 1 * 8192);
                f16x8 B2 = *(const f16x8*)(bb + 2 * 8192);
#pragma unroll
                for (int mf = 0; mf < 4; ++mf) {
                    accR[mf][nf]  = MFMA16(ah[mf], B0, accR[mf][nf]);
                    accZ[mf][nf]  = MFMA16(ah[mf], B1, accZ[mf][nf]);
                    accHN[mf][nf] = MFMA16(ah[mf], B2, accHN[mf][nf]);
                }
            }
        }
        __builtin_amdgcn_s_setprio(0);
        cur ^= 1;
    }

    // epilogue: batched GI gather per mf-group (ids/h_old preloaded), gate math
    float bh[2][3];
#pragma unroll
    for (int nf = 0; nf < 2; ++nf) {
        int col = c0 + wn * 32 + nf * 16 + l15;
        bh[nf][0] = b_hh[col];
        bh[nf][1] = b_hh[DD + col];
        bh[nf][2] = b_hh[2 * DD + col];
    }
#pragma unroll
    for (int mf = 0; mf < 4; ++mf) {
        float g0[2][4], g1[2][4], g2[2][4];
#pragma unroll
        for (int nf = 0; nf < 2; ++nf) {
            int col = c0 + wn * 32 + nf * 16 + l15;
#pragma unroll
            for (int r = 0; r < 4; ++r) {
                const f16* gr = gi + (size_t)srcrow[mf][r] * 1536 + col;
                g0[nf][r] = (float)gr[0];
                g1[nf][r] = (float)gr[512];
                g2[nf][r] = (float)gr[1024];
            }
        }
#pragma unroll
        for (int nf = 0; nf < 2; ++nf) {
            int col = c0 + wn * 32 + nf * 16 + l15;
#pragma unroll
            for (int r = 0; r < 4; ++r) {
                int row = row0 + wm * 64 + mf * 16 + lhi * 4 + r;
                size_t off = (size_t)row * DD + col;
                float R = fsigm(g0[nf][r] + accR[mf][nf][r] + bh[nf][0]);
                float Z = fsigm(g1[nf][r] + accZ[mf][nf][r] + bh[nf][1]);
                float N = ftanh(g2[nf][r] + R * (accHN[mf][nf][r] + bh[nf][2]));
                float res = (1.0f - Z) * N + Z * (float)hvp[mf][nf][r];
                if (LAST) f32w[off] = res;
                else      h16w[off] = (f16)res;
            }
        }
    }
}

// ---------------------------------------------------------------------------
extern "C" void kernel_launch(void* const* d_in, const int* in_sizes, int n_in,
                              void* d_out, int out_size, void* d_ws, size_t ws_size,
                              hipStream_t stream)
{
    const float* x    = (const float*)d_in[0];
    const float* w_ih = (const float*)d_in[1];
    const float* w_hh = (const float*)d_in[2];
    const float* b_ih = (const float*)d_in[3];
    const float* b_hh = (const float*)d_in[4];

    char* ws = (char*)d_ws;
    int*  ids = (int*)(ws + WS_IDS);
    f16*  w16 = (f16*)(ws + WS_W16);
    f16*  P0  = (f16*)(ws + WS_H16);       // ping
    f16*  P1  = (f16*)d_out;               // pong (aliases d_out; last step writes f32)
    f16*  gi  = (f16*)(ws + WS_GI);
    float* fo = (float*)d_out;

    const int has_x16 = (ws_size >= WS_NEED_X16) ? 1 : 0;
    f16* x16 = has_x16 ? (f16*)(ws + WS_X16) : nullptr;

    int prep_grid = SEL_BLOCKS + W_BLOCKS + (has_x16 ? X_BLOCKS : 0);
    prep_kernel<<<dim3(prep_grid), dim3(256), 0, stream>>>(
        x, ids, w_ih, w_hh, w16, x16, has_x16);

    if (has_x16)
        gi_gemm_kernel<true><<<dim3(3072), dim3(256), 0, stream>>>(x, x16, w16, b_ih, gi);
    else
        gi_gemm_kernel<false><<<dim3(3072), dim3(256), 0, stream>>>(x, x16, w16, b_ih, gi);

    step0_kernel<<<dim3(2048), dim3(256), 0, stream>>>(ids, gi, b_hh, P0);   // h1 -> P0

    for (int s = 1; s < WW; ++s) {
        const f16* hr = (s & 1) ? P0 : P1;
        if (s == WW - 1)
            gru_step_h_kernel<true><<<dim3(512), dim3(256), 0, stream>>>(
                ids, w16, b_hh, gi, hr, nullptr, fo, s);
        else
            gru_step_h_kernel<false><<<dim3(512), dim3(256), 0, stream>>>(
                ids, w16, b_hh, gi, hr, (s & 1) ? P1 : P0, nullptr, s);
    }
}

// Round 17
// 361.393 us; speedup vs baseline: 1.0213x; 1.0213x over previous
//
#include <hip/hip_runtime.h>
#include <math.h>

// Problem constants
#define BB 16
#define TT 2048
#define DD 512
#define WW 12
#define TQ 512
#define NROWS (BB * TQ)

typedef _Float16 f16;
typedef __attribute__((ext_vector_type(8))) _Float16 f16x8;
typedef __attribute__((ext_vector_type(4))) _Float16 f16x4;
typedef __attribute__((ext_vector_type(4))) float f32x4;

#define MFMA16(a, b, c) __builtin_amdgcn_mfma_f32_16x16x32_f16((a), (b), (c), 0, 0, 0)

// ws layout
#define WS_IDS  0u
#define WS_W16  (512u * 1024u)                  // 3072 x 512 f16 = 3 MB
#define WS_H16  (4u * 1024u * 1024u)            // 8192 x 512 f16 = 8 MB (ping)
#define WS_GI   (12u * 1024u * 1024u)           // 32768 x 1536 f16 = 96 MB
#define WS_X16  (108ull * 1024ull * 1024ull)    // 32768 x 512 f16 = 32 MB
#define WS_NEED_X16 (140ull * 1024ull * 1024ull)

// prep grid split
#define SEL_BLOCKS 2048
#define W_BLOCKS   1536
#define X_BLOCKS   16384

__device__ __forceinline__ float fsigm(float v) { return 1.0f / (1.0f + __expf(-v)); }
__device__ __forceinline__ float ftanh(float v) {
    float a = fabsf(v);
    float t = __expf(-2.0f * a);
    float r = (1.0f - t) / (1.0f + t);
    return copysignf(r, v);
}

__device__ __forceinline__ f16x8 cvt8(float4 a, float4 b) {
    f16x8 r;
    r[0] = (_Float16)a.x; r[1] = (_Float16)a.y; r[2] = (_Float16)a.z; r[3] = (_Float16)a.w;
    r[4] = (_Float16)b.x; r[5] = (_Float16)b.y; r[6] = (_Float16)b.z; r[7] = (_Float16)b.w;
    return r;
}

// -------- Kernel 1: merged prep = select + w16 + x16 (round-12 proven) ------
__global__ __launch_bounds__(256, 4) void prep_kernel(
    const float* __restrict__ x, int* __restrict__ ids,
    const float* __restrict__ wi, const float* __restrict__ wh,
    f16* __restrict__ w16, f16* __restrict__ x16, int has_x16)
{
    const int bid = blockIdx.x;
    const int tid = threadIdx.x;

    if (bid >= SEL_BLOCKS) {
        int rel = bid - SEL_BLOCKS;
        if (rel < W_BLOCKS) {
            const int PER = 3 * DD * DD / 4;
            int i = rel * 256 + tid;
            float4 v;
            if (i < PER) v = ((const float4*)wi)[i];
            else         v = ((const float4*)wh)[i - PER];
            f16x4 o;
            o[0] = (_Float16)v.x; o[1] = (_Float16)v.y; o[2] = (_Float16)v.z; o[3] = (_Float16)v.w;
            *(f16x4*)(w16 + (size_t)i * 4) = o;
        } else {
            int j = (rel - W_BLOCKS) * 256 + tid;
            float4 v = ((const float4*)x)[j];
            f16x4 o;
            o[0] = (_Float16)v.x; o[1] = (_Float16)v.y; o[2] = (_Float16)v.z; o[3] = (_Float16)v.w;
            *(f16x4*)(x16 + (size_t)j * 4) = o;
        }
        return;
    }

    const int wid = tid >> 6, lane = tid & 63;
    const int swz = (bid & 7) * 256 + (bid >> 3);
    const int n = swz * 4 + wid;
    const int b = n >> 9, qi = n & 511;

    int t = (qi == TQ - 1) ? (TT - 1)
          : (int)((double)qi * ((double)(TT - 1) / (double)(TQ - 1)));
    int j0 = t - (WW - 1); if (j0 < 0) j0 = 0;
    int j1 = t + (WW - 1); if (j1 > TT - 1) j1 = TT - 1;
    const int ncand = j1 - j0 + 1;

    const int c = lane & 3, i = lane >> 2;
    const float* qrow = x + ((size_t)b * TT + t) * DD + i * 4;

    float4 q[8];
#pragma unroll
    for (int it = 0; it < 8; ++it) q[it] = *(const float4*)(qrow + it * 64);

    double sv[6];
#pragma unroll
    for (int r = 0; r < 6; ++r) {
        int cc = r * 4 + c;
        int jr = j0 + cc; if (jr > j1) jr = j1;
        const float* krow = x + ((size_t)b * TT + jr) * DD + i * 4;
        double s0 = 0.0, s1 = 0.0;
#pragma unroll
        for (int it = 0; it < 8; ++it) {
            float4 kv = *(const float4*)(krow + it * 64);
            s0 = fma((double)q[it].x, (double)kv.x, s0);
            s1 = fma((double)q[it].y, (double)kv.y, s1);
            s0 = fma((double)q[it].z, (double)kv.z, s0);
            s1 = fma((double)q[it].w, (double)kv.w, s1);
        }
        sv[r] = s0 + s1;
    }

#pragma unroll
    for (int r = 0; r < 6; ++r) {
        double v = sv[r];
        v += __shfl_xor(v, 4);
        v += __shfl_xor(v, 8);
        v += __shfl_xor(v, 16);
        v += __shfl_xor(v, 32);
        sv[r] = v;
    }

    const int rr = lane >> 2;
    double sj = sv[0];
    sj = (rr == 1) ? sv[1] : sj;
    sj = (rr == 2) ? sv[2] : sj;
    sj = (rr == 3) ? sv[3] : sj;
    sj = (rr == 4) ? sv[4] : sj;
    sj = (rr == 5) ? sv[5] : sj;
    bool valid = lane < ncand;
    if (!valid) sj = -1.0e300;

    int rank = 0;
    for (int kk = 0; kk < 2 * WW - 1; ++kk) {
        if (kk >= ncand) break;
        double bs = __shfl(sj, kk);
        rank += (bs > sj || (bs == sj && kk < lane)) ? 1 : 0;
    }
    bool sel = valid && (rank < WW);
    unsigned long long m = __ballot(sel);
    if (sel) {
        int pos = __popcll(m & ((1ull << lane) - 1ull));
        ids[(size_t)n * WW + pos] = j0 + lane;
    }
}

// -------- Kernel 3: GI = x @ w_ih.T + b_ih (round-12 proven) ---------------
template<bool X16PATH>
__global__ __launch_bounds__(256, 2) void gi_gemm_kernel(
    const float* __restrict__ x,
    const f16* __restrict__ x16,
    const f16* __restrict__ w16,        // rows 0..1535 = w_ih
    const float* __restrict__ b_ih,
    f16* __restrict__ gi)               // [32768][1536]
{
    __shared__ __align__(16) char sB[2][16 * 1024];
    __shared__ __align__(16) char sX[2][16 * 1024];

    const int tid = threadIdx.x;
    const int lane = tid & 63, wid = tid >> 6;
    const int wm = wid >> 1, wn = wid & 1;
    const int l15 = lane & 15, lhi = lane >> 4;
    const int bid = blockIdx.x;
    const int xcd = bid & 7, idx = bid >> 3;
    const int rb = xcd * 32 + idx / 12;
    const int cb = idx % 12;
    const int row0 = rb * 128, c0 = cb * 128;

    const int slot = lane & 3, lc = lane >> 2;
    const f16* bsrc[4]; int bdst[4];
#pragma unroll
    for (int ii = 0; ii < 4; ++ii) {
        int ch = wid * 4 + ii;
        int half = ch >> 3, cg = ch & 7;
        int col = cg * 16 + lc;
        bsrc[ii] = w16 + ((size_t)(c0 + col) * 512 + half * 32
                          + (size_t)((slot ^ ((col >> 1) & 3)) * 8));
        bdst[ii] = half * 8192 + cg * 1024;
    }

    const f16* x16src[4]; int x16dst[4];
    const float* xps[2]; int xdst[2];
    if (X16PATH) {
        const int xrl = lane >> 2, xslot = lane & 3;
        const int xswz = (xslot ^ ((xrl >> 1) & 3)) * 8;
#pragma unroll
        for (int ii = 0; ii < 4; ++ii) {
            int ch2 = wid * 4 + ii;
            int hh = ch2 >> 3, ch = ch2 & 7;
            x16src[ii] = x16 + ((size_t)(row0 + ch * 16 + xrl) * 512 + hh * 32 + xswz);
            x16dst[ii] = hh * 8192 + ch * 1024;
        }
    } else {
#pragma unroll
        for (int seg = 0; seg < 2; ++seg) {
            int row = seg * 64 + (tid >> 2);
            int chunk = (tid & 3) ^ ((row >> 1) & 3);
            xps[seg] = x + (size_t)(row0 + row) * DD + chunk * 8;
            xdst[seg] = seg * 4096 + tid * 16;
        }
    }

    const int swzo = (lhi ^ ((l15 >> 1) & 3)) * 16;
    const int aBase = (wm * 64 + l15) * 64 + swzo;
    const int bBase = (wn * 64 + l15) * 64 + swzo;

    f32x4 acc[4][4];
#pragma unroll
    for (int mf = 0; mf < 4; ++mf)
#pragma unroll
        for (int nf = 0; nf < 4; ++nf) { f32x4 z = {0.f,0.f,0.f,0.f}; acc[mf][nf] = z; }

    {
#pragma unroll
        for (int ii = 0; ii < 4; ++ii)
            __builtin_amdgcn_global_load_lds(
                (const __attribute__((address_space(1))) unsigned*)bsrc[ii],
                (__attribute__((address_space(3))) unsigned*)(&sB[0][0] + bdst[ii]), 16, 0, 0);
        if (X16PATH) {
#pragma unroll
            for (int ii = 0; ii < 4; ++ii)
                __builtin_amdgcn_global_load_lds(
                    (const __attribute__((address_space(1))) unsigned*)x16src[ii],
                    (__attribute__((address_space(3))) unsigned*)(&sX[0][0] + x16dst[ii]), 16, 0, 0);
        } else {
#pragma unroll
            for (int seg = 0; seg < 2; ++seg)
#pragma unroll
                for (int h = 0; h < 2; ++h) {
                    float4 a0 = *(const float4*)(xps[seg] + h * 32);
                    float4 a1 = *(const float4*)(xps[seg] + h * 32 + 4);
                    *(f16x8*)(&sX[0][0] + h * 8192 + xdst[seg]) = cvt8(a0, a1);
                }
        }
    }

    int cur = 0;
    for (int ks = 0; ks < 8; ++ks) {
        asm volatile("s_waitcnt vmcnt(0)" ::: "memory");
        __syncthreads();

        const int kn = (ks + 1) * 64;
        float4 a[2][2][2];
        if (ks < 7) {
#pragma unroll
            for (int ii = 0; ii < 4; ++ii)
                __builtin_amdgcn_global_load_lds(
                    (const __attribute__((address_space(1))) unsigned*)(bsrc[ii] + kn),
                    (__attribute__((address_space(3))) unsigned*)(&sB[cur ^ 1][0] + bdst[ii]), 16, 0, 0);
            if (X16PATH) {
#pragma unroll
                for (int ii = 0; ii < 4; ++ii)
                    __builtin_amdgcn_global_load_lds(
                        (const __attribute__((address_space(1))) unsigned*)(x16src[ii] + kn),
                        (__attribute__((address_space(3))) unsigned*)(&sX[cur ^ 1][0] + x16dst[ii]), 16, 0, 0);
            } else {
#pragma unroll
                for (int seg = 0; seg < 2; ++seg)
#pragma unroll
                    for (int h = 0; h < 2; ++h) {
                        a[seg][h][0] = *(const float4*)(xps[seg] + kn + h * 32);
                        a[seg][h][1] = *(const float4*)(xps[seg] + kn + h * 32 + 4);
                    }
            }
        }

        __builtin_amdgcn_s_setprio(1);
#pragma unroll
        for (int h = 0; h < 2; ++h) {
            f16x8 ax[4];
#pragma unroll
            for (int mf = 0; mf < 4; ++mf)
                ax[mf] = *(const f16x8*)(&sX[cur][0] + h * 8192 + aBase + mf * 1024);
#pragma unroll
            for (int nf = 0; nf < 4; ++nf) {
                f16x8 Bv = *(const f16x8*)(&sB[cur][0] + h * 8192 + bBase + nf * 1024);
#pragma unroll
                for (int mf = 0; mf < 4; ++mf)
                    acc[mf][nf] = MFMA16(ax[mf], Bv, acc[mf][nf]);
            }
        }
        __builtin_amdgcn_s_setprio(0);

        if (!X16PATH && ks < 7) {
#pragma unroll
            for (int seg = 0; seg < 2; ++seg)
#pragma unroll
                for (int h = 0; h < 2; ++h)
                    *(f16x8*)(&sX[cur ^ 1][0] + h * 8192 + xdst[seg]) = cvt8(a[seg][h][0], a[seg][h][1]);
        }
        cur ^= 1;
    }

#pragma unroll
    for (int nf = 0; nf < 4; ++nf) {
        int col = c0 + wn * 64 + nf * 16 + l15;
        float bi = b_ih[col];
#pragma unroll
        for (int mf = 0; mf < 4; ++mf)
#pragma unroll
            for (int r = 0; r < 4; ++r) {
                int row = row0 + wm * 64 + mf * 16 + lhi * 4 + r;
                gi[(size_t)row * 1536 + col] = (f16)(acc[mf][nf][r] + bi);
            }
    }
}

// -------- Kernel 4: step 0 elementwise (h0 = 0) ----------------------------
__global__ __launch_bounds__(256) void step0_kernel(
    const int* __restrict__ ids, const f16* __restrict__ gi,
    const float* __restrict__ b_hh, f16* __restrict__ h16w)
{
    int g = blockIdx.x * 256 + threadIdx.x;
    int row = g >> 6;
    int c8 = (g & 63) * 8;
    int src = (row >> 9) * TT + ids[(size_t)row * WW + 0];
    const f16* gr = gi + (size_t)src * 1536 + c8;
    f16x8 vr = *(const f16x8*)(gr);
    f16x8 vz = *(const f16x8*)(gr + 512);
    f16x8 vn = *(const f16x8*)(gr + 1024);
    f16x8 out;
#pragma unroll
    for (int j = 0; j < 8; ++j) {
        int col = c8 + j;
        float R = fsigm((float)vr[j] + b_hh[col]);
        float Z = fsigm((float)vz[j] + b_hh[DD + col]);
        float N = ftanh((float)vn[j] + R * b_hh[2 * DD + col]);
        out[j] = (f16)((1.0f - Z) * N);
    }
    *(f16x8*)(h16w + (size_t)row * DD + c8) = out;
}

// -------- Kernel 5: h-side GRU step (round-15 proven core) -----------------
// 256 thr / 4 waves; tile 128 rows x 64 cols; grid 512 = 64 rb x 8 cb.
// LDS 80 KB (2 blocks/CU): B 2x24KB, h 2x16KB; 8-slot-row XOR swizzle via
// pre-swizzled-source global_load_lds; vmcnt(0)+syncthreads per phase.
// LAST templatizes the output path (f32 to d_out vs f16 ping-pong).
template<bool LAST>
__global__ __launch_bounds__(256, 2) void gru_step_h_kernel(
    const int* __restrict__ ids,
    const f16* __restrict__ w16,        // rows 1536..3071 = w_hh
    const float* __restrict__ b_hh,
    const f16* __restrict__ gi,
    const f16* __restrict__ h16r,
    f16* __restrict__ h16w,
    float* __restrict__ f32w,
    int step)
{
    __shared__ __align__(16) char sB[2][24 * 1024];
    __shared__ __align__(16) char sH[2][16 * 1024];

    const int tid = threadIdx.x;
    const int lane = tid & 63, wid = tid >> 6;
    const int wm = wid >> 1, wn = wid & 1;
    const int l15 = lane & 15, lhi = lane >> 4;
    const int bid = blockIdx.x;
    const int xcd = bid & 7, idx = bid >> 3;
    const int rb = xcd * 8 + (idx & 7);
    const int cb = idx >> 3;
    const int row0 = rb * 128, c0 = cb * 64;

    const int lrow = lane >> 3, lslot = lane & 7;
    const int sswz = (lslot ^ lrow) * 8;

    const f16* bsrc[6]; int bdst[6];
#pragma unroll
    for (int ii = 0; ii < 6; ++ii) {
        int ch = wid * 6 + ii;
        int gate = ch >> 3, cg = ch & 7;
        int col = cg * 8 + lrow;
        bsrc[ii] = w16 + ((size_t)(1536 + gate * 512 + c0 + col) * 512 + sswz);
        bdst[ii] = gate * 8192 + cg * 1024 + lrow * 128 + lslot * 16;
    }
    const f16* hsrc[4]; int hdst[4];
#pragma unroll
    for (int ii = 0; ii < 4; ++ii) {
        int ch = wid * 4 + ii;
        int hrow = ch * 8 + lrow;
        hsrc[ii] = h16r + ((size_t)(row0 + hrow) * 512 + sswz);
        hdst[ii] = ch * 1024 + lrow * 128 + lslot * 16;
    }

    const int rowrd = wm * 64 + l15;
    const int colrd = wn * 32 + l15;
    int aOff[4][2], bOff[2][2];
#pragma unroll
    for (int mf = 0; mf < 4; ++mf)
#pragma unroll
        for (int h = 0; h < 2; ++h) {
            int rr2 = rowrd + mf * 16;
            aOff[mf][h] = rr2 * 128 + ((((h << 2) | lhi) ^ (rr2 & 7)) << 4);
        }
#pragma unroll
    for (int nf = 0; nf < 2; ++nf)
#pragma unroll
        for (int h = 0; h < 2; ++h) {
            int cc = colrd + nf * 16;
            bOff[nf][h] = cc * 128 + ((((h << 2) | lhi) ^ (cc & 7)) << 4);
        }

    f32x4 accR[4][2], accZ[4][2], accHN[4][2];
#pragma unroll
    for (int mf = 0; mf < 4; ++mf)
#pragma unroll
        for (int nf = 0; nf < 2; ++nf) {
            f32x4 z = {0.f, 0.f, 0.f, 0.f};
            accR[mf][nf] = z; accZ[mf][nf] = z; accHN[mf][nf] = z;
        }

    // prologue: fill buffer 0
#pragma unroll
    for (int ii = 0; ii < 6; ++ii)
        __builtin_amdgcn_global_load_lds(
            (const __attribute__((address_space(1))) unsigned*)bsrc[ii],
            (__attribute__((address_space(3))) unsigned*)(&sB[0][0] + bdst[ii]), 16, 0, 0);
#pragma unroll
    for (int ii = 0; ii < 4; ++ii)
        __builtin_amdgcn_global_load_lds(
            (const __attribute__((address_space(1))) unsigned*)hsrc[ii],
            (__attribute__((address_space(3))) unsigned*)(&sH[0][0] + hdst[ii]), 16, 0, 0);

    int cur = 0;
    for (int ks = 0; ks < 8; ++ks) {
        asm volatile("s_waitcnt vmcnt(0)" ::: "memory");
        __syncthreads();

        const int kn = (ks + 1) * 64;
        if (ks < 7) {
#pragma unroll
            for (int ii = 0; ii < 6; ++ii)
                __builtin_amdgcn_global_load_lds(
                    (const __attribute__((address_space(1))) unsigned*)(bsrc[ii] + kn),
                    (__attribute__((address_space(3))) unsigned*)(&sB[cur ^ 1][0] + bdst[ii]), 16, 0, 0);
#pragma unroll
            for (int ii = 0; ii < 4; ++ii)
                __builtin_amdgcn_global_load_lds(
                    (const __attribute__((address_space(1))) unsigned*)(hsrc[ii] + kn),
                    (__attribute__((address_space(3))) unsigned*)(&sH[cur ^ 1][0] + hdst[ii]), 16, 0, 0);
        }

        __builtin_amdgcn_s_setprio(1);
#pragma unroll
        for (int h = 0; h < 2; ++h) {
            f16x8 ah[4];
#pragma unroll
            for (int mf = 0; mf < 4; ++mf)
                ah[mf] = *(const f16x8*)(&sH[cur][0] + aOff[mf][h]);
#pragma unroll
            for (int nf = 0; nf < 2; ++nf) {
                const char* bb = &sB[cur][0] + bOff[nf][h];
                f16x8 B0 = *(const f16x8*)(bb + 0 * 8192);
                f16x8 B1 = *(const f16x8*)(bb + 1 * 8192);
                f16x8 B2 = *(const f16x8*)(bb + 2 * 8192);
#pragma unroll
                for (int mf = 0; mf < 4; ++mf) {
                    accR[mf][nf]  = MFMA16(ah[mf], B0, accR[mf][nf]);
                    accZ[mf][nf]  = MFMA16(ah[mf], B1, accZ[mf][nf]);
                    accHN[mf][nf] = MFMA16(ah[mf], B2, accHN[mf][nf]);
                }
            }
        }
        __builtin_amdgcn_s_setprio(0);
        cur ^= 1;
    }

    // epilogue: batched GI/h gather per mf-group (ids gather CSE'd), gate math
    float bh[2][3];
#pragma unroll
    for (int nf = 0; nf < 2; ++nf) {
        int col = c0 + wn * 32 + nf * 16 + l15;
        bh[nf][0] = b_hh[col];
        bh[nf][1] = b_hh[DD + col];
        bh[nf][2] = b_hh[2 * DD + col];
    }
#pragma unroll
    for (int mf = 0; mf < 4; ++mf) {
        int srcrow[4];
#pragma unroll
        for (int r = 0; r < 4; ++r) {
            int row = row0 + wm * 64 + mf * 16 + lhi * 4 + r;
            srcrow[r] = (row >> 9) * TT + ids[(size_t)row * WW + step];
        }
        float g0[2][4], g1[2][4], g2[2][4], hv[2][4];
#pragma unroll
        for (int nf = 0; nf < 2; ++nf) {
            int col = c0 + wn * 32 + nf * 16 + l15;
#pragma unroll
            for (int r = 0; r < 4; ++r) {
                int row = row0 + wm * 64 + mf * 16 + lhi * 4 + r;
                const f16* gr = gi + (size_t)srcrow[r] * 1536 + col;
                g0[nf][r] = (float)gr[0];
                g1[nf][r] = (float)gr[512];
                g2[nf][r] = (float)gr[1024];
                hv[nf][r] = (float)h16r[(size_t)row * DD + col];
            }
        }
#pragma unroll
        for (int nf = 0; nf < 2; ++nf) {
            int col = c0 + wn * 32 + nf * 16 + l15;
#pragma unroll
            for (int r = 0; r < 4; ++r) {
                int row = row0 + wm * 64 + mf * 16 + lhi * 4 + r;
                size_t off = (size_t)row * DD + col;
                float R = fsigm(g0[nf][r] + accR[mf][nf][r] + bh[nf][0]);
                float Z = fsigm(g1[nf][r] + accZ[mf][nf][r] + bh[nf][1]);
                float N = ftanh(g2[nf][r] + R * (accHN[mf][nf][r] + bh[nf][2]));
                float res = (1.0f - Z) * N + Z * hv[nf][r];
                if (LAST) f32w[off] = res;
                else      h16w[off] = (f16)res;
            }
        }
    }
}

// ---------------------------------------------------------------------------
extern "C" void kernel_launch(void* const* d_in, const int* in_sizes, int n_in,
                              void* d_out, int out_size, void* d_ws, size_t ws_size,
                              hipStream_t stream)
{
    const float* x    = (const float*)d_in[0];
    const float* w_ih = (const float*)d_in[1];
    const float* w_hh = (const float*)d_in[2];
    const float* b_ih = (const float*)d_in[3];
    const float* b_hh = (const float*)d_in[4];

    char* ws = (char*)d_ws;
    int*  ids = (int*)(ws + WS_IDS);
    f16*  w16 = (f16*)(ws + WS_W16);
    f16*  P0  = (f16*)(ws + WS_H16);       // ping
    f16*  P1  = (f16*)d_out;               // pong (aliases d_out; last step writes f32)
    f16*  gi  = (f16*)(ws + WS_GI);
    float* fo = (float*)d_out;

    const int has_x16 = (ws_size >= WS_NEED_X16) ? 1 : 0;
    f16* x16 = has_x16 ? (f16*)(ws + WS_X16) : nullptr;

    int prep_grid = SEL_BLOCKS + W_BLOCKS + (has_x16 ? X_BLOCKS : 0);
    prep_kernel<<<dim3(prep_grid), dim3(256), 0, stream>>>(
        x, ids, w_ih, w_hh, w16, x16, has_x16);

    if (has_x16)
        gi_gemm_kernel<true><<<dim3(3072), dim3(256), 0, stream>>>(x, x16, w16, b_ih, gi);
    else
        gi_gemm_kernel<false><<<dim3(3072), dim3(256), 0, stream>>>(x, x16, w16, b_ih, gi);

    step0_kernel<<<dim3(2048), dim3(256), 0, stream>>>(ids, gi, b_hh, P0);   // h1 -> P0

    for (int s = 1; s < WW; ++s) {
        const f16* hr = (s & 1) ? P0 : P1;
        if (s == WW - 1)
            gru_step_h_kernel<true><<<dim3(512), dim3(256), 0, stream>>>(
                ids, w16, b_hh, gi, hr, nullptr, fo, s);
        else
            gru_step_h_kernel<false><<<dim3(512), dim3(256), 0, stream>>>(
                ids, w16, b_hh, gi, hr, (s & 1) ? P1 : P0, nullptr, s);
    }
}